// Round 2
// baseline (344.187 us; speedup 1.0000x reference)
//
#include <hip/hip_runtime.h>
#include <stdint.h>

// GLSTM: B=16, T=96, N=325, D=64, H=64. 5200 independent rows, 96-step recurrence.
// R4: two independent 16-row groups per block (512 thr, 8 waves). Waves 0-3 own
// group 2*bid, waves 4-7 own group 2*bid+1. Grid = 163 blocks <= 256 CUs ->
// exactly one block per CU (kills the 325-on-256 load imbalance) and 2 waves/SIMD
// interleave the per-step latency chain. Last block's upper half clamps to group
// 324 (duplicate identical stores, benign).
// Per-group structure unchanged from R3: column-sliced gate tiles (wave owns
// h-cols w*16..w*16+15 across all six gates -> elementwise fully in-register),
// single barrier/step, XOR-swizzled bf16 LDS tiles, merged-rcp sigmoids,
// exp2-with-folded-bias, v_cvt_pk_bf16_f32 packing.

#define TT 96
#define NNROW 325
#define STEP_OFS 20800          // N*D floats per time step
#define HT_OFS 31948800
#define CT_OFS 32281600

typedef __attribute__((ext_vector_type(8))) short short8;
typedef __attribute__((ext_vector_type(4))) float f32x4;

// barrier that does NOT drain vmcnt (prefetch loads / h-stores stay in flight)
#define BAR() asm volatile("s_waitcnt lgkmcnt(0)\n\ts_barrier" ::: "memory")

__device__ __forceinline__ short f2bf(float f) {
    union { float f; uint32_t u; } v; v.f = f;
    uint32_t r = (v.u + 0x7FFFu + ((v.u >> 16) & 1u)) >> 16;
    return (short)(r & 0xFFFFu);
}
__device__ __forceinline__ float frcp(float x) { return __builtin_amdgcn_rcpf(x); }
__device__ __forceinline__ float ex2(float x)  { return __builtin_amdgcn_exp2f(x); }
__device__ __forceinline__ uint32_t cvtpk(float lo, float hi) {
    uint32_t r;
    asm("v_cvt_pk_bf16_f32 %0, %1, %2" : "=v"(r) : "v"(lo), "v"(hi));
    return r;
}

__global__ __launch_bounds__(512, 1)
void glstm_kernel(const float* __restrict__ x,
                  const float* __restrict__ o_s,
                  const float* __restrict__ U_x,
                  const float* __restrict__ V_x,
                  const float* __restrict__ b_x,
                  const float* __restrict__ U_g,
                  const float* __restrict__ V_g,
                  const float* __restrict__ b_g,
                  float* __restrict__ out)
{
    // per-half double-buffered bf16 tiles, [half][parity][16][64] shorts.
    // 16B blocks XOR-swizzled by (row&7): elem(m,k) at m*64 + ((k>>3 ^ (m&7))<<3 | (k&7))
    __shared__ __align__(16) short Xb[2][2][1024];   // 8 KB
    __shared__ __align__(16) short Ob[2][2][1024];   // 8 KB
    __shared__ __align__(16) short Hb[2][2][1024];   // 8 KB

    const int tid  = threadIdx.x;
    const int half = tid >> 8;        // which group this wave serves
    const int t8   = tid & 255;       // thread index within the half
    int g = blockIdx.x * 2 + half;    // row-group 0..325
    if (g > NNROW - 1) g = NNROW - 1; // clamp (duplicate work, identical stores)
    const int lane = tid & 63;
    const int w    = (t8 >> 6);       // wave-in-half 0..3 -> h-col slice w*16..
    const int q    = lane >> 4;       // quad 0..3
    const int ln   = lane & 15;       // row (A) / col (B,C) within tile

    // ---------------- weights: per-wave column-slice B-fragments ------------
    short8 fWx[4][2], fWh[4][2], fGo[2][2], fGh[2][2];
    #pragma unroll
    for (int gt = 0; gt < 4; ++gt) {
        const int col = gt * 64 + w * 16 + ln;
        #pragma unroll
        for (int kb = 0; kb < 2; ++kb) {
            short8 a, b;
            #pragma unroll
            for (int j = 0; j < 8; ++j) {
                const int row = kb * 32 + q * 8 + j;
                a[j] = f2bf(U_x[(size_t)row * 256 + col]);
                b[j] = f2bf(V_x[(size_t)row * 256 + col]);
            }
            fWx[gt][kb] = a; fWh[gt][kb] = b;
        }
    }
    #pragma unroll
    for (int gt = 0; gt < 2; ++gt) {
        const int col = gt * 64 + w * 16 + ln;
        #pragma unroll
        for (int kb = 0; kb < 2; ++kb) {
            short8 a, b;
            #pragma unroll
            for (int j = 0; j < 8; ++j) {
                const int row = kb * 32 + q * 8 + j;
                a[j] = f2bf(U_g[(size_t)row * 128 + col]);
                b[j] = f2bf(V_g[(size_t)row * 128 + col]);
            }
            fGo[gt][kb] = a; fGh[gt][kb] = b;
        }
    }

    // ---------------- staging mapping (x / o_s -> LDS, coalesced) -----------
    const int sm = t8 >> 4;           // row within group 0..15
    const int sd = t8 & 15;           // 4-float chunk 0..15 (k = sd*4..sd*4+3)
    const int srow = g * 16 + sm;
    const int sb = srow / NNROW;
    const int sn = srow - sb * NNROW;
    const size_t sbase = ((size_t)(sb * TT) * NNROW + sn) * 64 + sd * 4;
    // swizzled store offset (bytes): block sd>>1, half-of-block sd&1
    const int stofs = (sm * 64 + (((sd >> 1) ^ (sm & 7)) << 3) + (sd & 1) * 4) * 2;

    // ---------------- A-fragment read offsets (bytes, swizzled) -------------
    const int o0 = ln * 128 + (((q    ) ^ (ln & 7)) << 4);   // k-blocks 0..3
    const int o1 = ln * 128 + (((4 + q) ^ (ln & 7)) << 4);   // k-blocks 4..7

    // ---------------- elementwise mapping (in-register gates) ---------------
    const int ch = w * 16 + ln;       // h-col 0..63
    const float NL2E = -1.44269504f;
    const float nbf  = NL2E * b_x[ch];
    const float nbi  = NL2E * b_x[64  + ch];
    const float nbo  = NL2E * b_x[128 + ch];
    const float nbu  = NL2E * b_x[192 + ch];
    const float nbgf = NL2E * b_g[ch];
    const float nbgu = NL2E * b_g[64 + ch];

    size_t obase[4];
    int    fo[4];
    int    hofs[4];
    #pragma unroll
    for (int e = 0; e < 4; ++e) {
        const int m = q * 4 + e;          // C layout: row = (lane>>4)*4 + reg
        const int row = g * 16 + m;
        const int b = row / NNROW;
        const int n = row - b * NNROW;
        obase[e] = ((size_t)(b * TT) * NNROW + n) * 64 + ch;
        fo[e]    = (b * NNROW + n) * 64 + ch;
        hofs[e]  = m * 64 + ((((ch >> 3) ^ (m & 7)) << 3) | (ch & 7));
    }
    float ct4[4] = {0.f, 0.f, 0.f, 0.f};

    short* const Xh = &Xb[half][0][0];
    short* const Oh = &Ob[half][0][0];
    short* const Hh = &Hb[half][0][0];

    // ---------------- prologue: stage t=0, zero h, prefetch t=1,2 -----------
    {
        float4 x0 = *(const float4*)(x   + sbase);
        float4 s0 = *(const float4*)(o_s + sbase);
        uint2 sx; sx.x = cvtpk(x0.x, x0.y); sx.y = cvtpk(x0.z, x0.w);
        uint2 so; so.x = cvtpk(s0.x, s0.y); so.y = cvtpk(s0.z, s0.w);
        *(uint2*)((char*)Xh + stofs) = sx;
        *(uint2*)((char*)Oh + stofs) = so;
        uint2 z; z.x = 0u; z.y = 0u;
        *(uint2*)((char*)Hh + t8 * 8) = z;
    }
    float4 xqA = *(const float4*)(x   + sbase + 1 * (size_t)STEP_OFS);
    float4 oqA = *(const float4*)(o_s + sbase + 1 * (size_t)STEP_OFS);
    float4 xqB = *(const float4*)(x   + sbase + 2 * (size_t)STEP_OFS);
    float4 oqB = *(const float4*)(o_s + sbase + 2 * (size_t)STEP_OFS);
    BAR();

    auto step = [&](int t, float4& xq, float4& oq) {
        const int p  = t & 1;
        const int pn = p ^ 1;
        const char* xb = (const char*)Xh + p * 2048;
        const char* ob = (const char*)Oh + p * 2048;
        const char* hb = (const char*)Hh + p * 2048;
        const short8 ax0 = *(const short8*)(xb + o0);
        const short8 ax1 = *(const short8*)(xb + o1);
        const short8 ao0 = *(const short8*)(ob + o0);
        const short8 ao1 = *(const short8*)(ob + o1);
        const short8 ah0 = *(const short8*)(hb + o0);
        const short8 ah1 = *(const short8*)(hb + o1);

        // ---- MFMA: 4 gate tiles + 2 gov tiles, all gates for this wave's cols
        f32x4 aF[4], aG[2];
        #pragma unroll
        for (int gt = 0; gt < 4; ++gt) {
            f32x4 acc = {0.f, 0.f, 0.f, 0.f};
            acc = __builtin_amdgcn_mfma_f32_16x16x32_bf16(ax0, fWx[gt][0], acc, 0, 0, 0);
            acc = __builtin_amdgcn_mfma_f32_16x16x32_bf16(ax1, fWx[gt][1], acc, 0, 0, 0);
            acc = __builtin_amdgcn_mfma_f32_16x16x32_bf16(ah0, fWh[gt][0], acc, 0, 0, 0);
            acc = __builtin_amdgcn_mfma_f32_16x16x32_bf16(ah1, fWh[gt][1], acc, 0, 0, 0);
            aF[gt] = acc;
        }
        #pragma unroll
        for (int gt = 0; gt < 2; ++gt) {
            f32x4 acc = {0.f, 0.f, 0.f, 0.f};
            acc = __builtin_amdgcn_mfma_f32_16x16x32_bf16(ao0, fGo[gt][0], acc, 0, 0, 0);
            acc = __builtin_amdgcn_mfma_f32_16x16x32_bf16(ao1, fGo[gt][1], acc, 0, 0, 0);
            acc = __builtin_amdgcn_mfma_f32_16x16x32_bf16(ah0, fGh[gt][0], acc, 0, 0, 0);
            acc = __builtin_amdgcn_mfma_f32_16x16x32_bf16(ah1, fGh[gt][1], acc, 0, 0, 0);
            aG[gt] = acc;
        }

        // ---- stage x/os(t+1) into buffers[pn]; reload regs with t+3 --------
        // (independent of MFMA results -> fills the MFMA latency shadow)
        {
            uint2 sx; sx.x = cvtpk(xq.x, xq.y); sx.y = cvtpk(xq.z, xq.w);
            uint2 so; so.x = cvtpk(oq.x, oq.y); so.y = cvtpk(oq.z, oq.w);
            *(uint2*)((char*)Xh + pn * 2048 + stofs) = sx;
            *(uint2*)((char*)Oh + pn * 2048 + stofs) = so;
            int tn = t + 3; if (tn > TT - 1) tn = TT - 1;
            xq = *(const float4*)(x   + sbase + (size_t)tn * STEP_OFS);
            oq = *(const float4*)(o_s + sbase + (size_t)tn * STEP_OFS);
        }

        // ---- elementwise (in-register): merged-rcp sigmoid products --------
        const size_t tofs = (size_t)t * STEP_OFS;
        float hv[4];
        #pragma unroll
        for (int e = 0; e < 4; ++e) {
            float ef  = ex2(fmaf(aF[0][e], NL2E, nbf));    // e^{-(f+bf)}
            float ei  = ex2(fmaf(aF[1][e], NL2E, nbi));
            float eo  = ex2(fmaf(aF[2][e], NL2E, nbo));
            float eu  = ex2(fmaf(aF[3][e], NL2E, nbu));
            float egf = ex2(fmaf(aG[0][e], NL2E, nbgf));
            float egu = ex2(fmaf(aG[1][e], NL2E, nbgu));
            float rf = frcp((1.f + ef) * (1.f + egf));                 // sig(f)*sig(gf)
            float ru = frcp(((1.f + ei) * (1.f + eu)) * (1.f + egu));  // sig(i)*sig(u)*sig(gu)
            float c  = fmaf(ct4[e], rf, ru);
            ct4[e] = c;
            float E  = ex2(c * 2.88539008f);                           // e^{2c}
            float th = fmaf(-2.f, frcp(E + 1.f), 1.f);                 // tanh, inf-safe
            float h  = th * frcp(1.f + eo);
            hv[e] = h;
            out[obase[e] + tofs] = h;
            if (t == TT - 1) {
                out[HT_OFS + fo[e]] = h;
                out[CT_OFS + fo[e]] = c;
            }
        }

        // ---- h -> LDS (bf16, swizzled) for next step -----------------------
        {
            union { uint32_t u; short s[2]; } h01, h23;
            h01.u = cvtpk(hv[0], hv[1]);
            h23.u = cvtpk(hv[2], hv[3]);
            short* hn = (short*)((char*)Hh + pn * 2048);
            hn[hofs[0]] = h01.s[0];
            hn[hofs[1]] = h01.s[1];
            hn[hofs[2]] = h23.s[0];
            hn[hofs[3]] = h23.s[1];
        }
        BAR();  // the ONLY barrier per step: h(t) + x/os(t+1) visible
    };

    for (int t = 0; t < TT; t += 2) {
        step(t,     xqA, oqA);
        step(t + 1, xqB, oqB);
    }
}

extern "C" void kernel_launch(void* const* d_in, const int* in_sizes, int n_in,
                              void* d_out, int out_size, void* d_ws, size_t ws_size,
                              hipStream_t stream) {
    const float* x   = (const float*)d_in[0];
    const float* o_s = (const float*)d_in[1];
    const float* U_x = (const float*)d_in[2];
    const float* V_x = (const float*)d_in[3];
    const float* b_x = (const float*)d_in[4];
    const float* U_g = (const float*)d_in[5];
    const float* V_g = (const float*)d_in[6];
    const float* b_g = (const float*)d_in[7];
    float* out = (float*)d_out;

    glstm_kernel<<<dim3(163), dim3(512), 0, stream>>>(x, o_s, U_x, V_x, b_x, U_g, V_g, b_g, out);
}

// Round 3
// 340.815 us; speedup vs baseline: 1.0099x; 1.0099x over previous
//
#include <hip/hip_runtime.h>
#include <stdint.h>

// GLSTM: B=16, T=96, N=325, D=64, H=64. 5200 rows, 96-step recurrence.
// R5: software-pipelined x-part. xacc(t) (x@U_x, os@U_g: 12 MFMAs) is computed
// during step t-1, so after each barrier the critical path is only:
// ds_read h-frags -> 12 two-deep h@V MFMAs -> elementwise -> h write.
// The x-MFMAs for t+1 + x-frag ds_reads are h-independent filler that the
// scheduler issues inside the lgkm/MFMA stall windows. x/os staged 2 steps
// ahead (double-buffered), h double-buffered; one barrier per step.
// Trans count 11->9/element: single-rcp cell path
//   c = (c_prev*P2 + P1)*rcp(P1*P2),
// and merged tanh*sig(o): h = (E-1)*rcp((E+1)*(1+eo)), E = exp2(min(2.885c,60))
// (clamp is exact for tanh and keeps the merged form inf-safe).
// Layout/swizzle/grid unchanged from R4 (2 groups/block, 163 blocks, 512 thr).

#define TT 96
#define NNROW 325
#define STEP_OFS 20800          // N*D floats per time step
#define HT_OFS 31948800
#define CT_OFS 32281600

typedef __attribute__((ext_vector_type(8))) short short8;
typedef __attribute__((ext_vector_type(4))) float f32x4;

// barrier that does NOT drain vmcnt (prefetch loads / h-stores stay in flight)
#define BAR() asm volatile("s_waitcnt lgkmcnt(0)\n\ts_barrier" ::: "memory")

__device__ __forceinline__ short f2bf(float f) {
    union { float f; uint32_t u; } v; v.f = f;
    uint32_t r = (v.u + 0x7FFFu + ((v.u >> 16) & 1u)) >> 16;
    return (short)(r & 0xFFFFu);
}
__device__ __forceinline__ float frcp(float x) { return __builtin_amdgcn_rcpf(x); }
__device__ __forceinline__ float ex2(float x)  { return __builtin_amdgcn_exp2f(x); }
__device__ __forceinline__ uint32_t cvtpk(float lo, float hi) {
    uint32_t r;
    asm("v_cvt_pk_bf16_f32 %0, %1, %2" : "=v"(r) : "v"(lo), "v"(hi));
    return r;
}

__global__ __launch_bounds__(512, 1)
void glstm_kernel(const float* __restrict__ x,
                  const float* __restrict__ o_s,
                  const float* __restrict__ U_x,
                  const float* __restrict__ V_x,
                  const float* __restrict__ b_x,
                  const float* __restrict__ U_g,
                  const float* __restrict__ V_g,
                  const float* __restrict__ b_g,
                  float* __restrict__ out)
{
    // [half][parity][16][64] bf16 tiles; 16B blocks XOR-swizzled by (row&7):
    // elem(m,k) at m*64 + ((k>>3 ^ (m&7))<<3 | (k&7))
    __shared__ __align__(16) short Xb[2][2][1024];   // 8 KB
    __shared__ __align__(16) short Ob[2][2][1024];   // 8 KB
    __shared__ __align__(16) short Hb[2][2][1024];   // 8 KB

    const int tid  = threadIdx.x;
    const int half = tid >> 8;
    const int t8   = tid & 255;
    int g = blockIdx.x * 2 + half;
    if (g > NNROW - 1) g = NNROW - 1;   // duplicate work, identical stores
    const int lane = tid & 63;
    const int w    = t8 >> 6;           // wave-in-half -> h-col slice w*16..
    const int q    = lane >> 4;
    const int ln   = lane & 15;

    // ---------------- weights: per-wave column-slice B-fragments ------------
    short8 fWx[4][2], fWh[4][2], fGo[2][2], fGh[2][2];
    #pragma unroll
    for (int gt = 0; gt < 4; ++gt) {
        const int col = gt * 64 + w * 16 + ln;
        #pragma unroll
        for (int kb = 0; kb < 2; ++kb) {
            short8 a, b;
            #pragma unroll
            for (int j = 0; j < 8; ++j) {
                const int row = kb * 32 + q * 8 + j;
                a[j] = f2bf(U_x[(size_t)row * 256 + col]);
                b[j] = f2bf(V_x[(size_t)row * 256 + col]);
            }
            fWx[gt][kb] = a; fWh[gt][kb] = b;
        }
    }
    #pragma unroll
    for (int gt = 0; gt < 2; ++gt) {
        const int col = gt * 64 + w * 16 + ln;
        #pragma unroll
        for (int kb = 0; kb < 2; ++kb) {
            short8 a, b;
            #pragma unroll
            for (int j = 0; j < 8; ++j) {
                const int row = kb * 32 + q * 8 + j;
                a[j] = f2bf(U_g[(size_t)row * 128 + col]);
                b[j] = f2bf(V_g[(size_t)row * 128 + col]);
            }
            fGo[gt][kb] = a; fGh[gt][kb] = b;
        }
    }

    // ---------------- staging mapping (x / o_s -> LDS, coalesced) -----------
    const int sm = t8 >> 4;
    const int sd = t8 & 15;
    const int srow = g * 16 + sm;
    const int sb = srow / NNROW;
    const int sn = srow - sb * NNROW;
    const size_t sbase = ((size_t)(sb * TT) * NNROW + sn) * 64 + sd * 4;
    const int stofs = (sm * 64 + (((sd >> 1) ^ (sm & 7)) << 3) + (sd & 1) * 4) * 2;

    // ---------------- A-fragment read offsets (bytes, swizzled) -------------
    const int o0 = ln * 128 + (((q    ) ^ (ln & 7)) << 4);
    const int o1 = ln * 128 + (((4 + q) ^ (ln & 7)) << 4);

    // ---------------- elementwise mapping -----------------------------------
    const int ch = w * 16 + ln;
    const float NL2E = -1.44269504f;
    const float nbf  = NL2E * b_x[ch];
    const float nbi  = NL2E * b_x[64  + ch];
    const float nbo  = NL2E * b_x[128 + ch];
    const float nbu  = NL2E * b_x[192 + ch];
    const float nbgf = NL2E * b_g[ch];
    const float nbgu = NL2E * b_g[64 + ch];

    int obase[4], fo[4], hofs[4];
    #pragma unroll
    for (int e = 0; e < 4; ++e) {
        const int m = q * 4 + e;          // C layout: row = (lane>>4)*4 + reg
        const int row = g * 16 + m;
        const int b = row / NNROW;
        const int n = row - b * NNROW;
        obase[e] = ((b * TT) * NNROW + n) * 64 + ch;   // < 2^25, int ok
        fo[e]    = (b * NNROW + n) * 64 + ch;
        hofs[e]  = m * 64 + ((((ch >> 3) ^ (m & 7)) << 3) | (ch & 7));
    }
    float ct4[4] = {0.f, 0.f, 0.f, 0.f};

    short* const Xh = &Xb[half][0][0];
    short* const Oh = &Ob[half][0][0];
    short* const Hh = &Hb[half][0][0];

    // ---------------- prologue ----------------------------------------------
    // stage x(0)->buf0, x(1)->buf1; zero h(-1) in Hb buf0; prefetch x(2),x(3)
    {
        float4 x0 = *(const float4*)(x   + sbase);
        float4 s0 = *(const float4*)(o_s + sbase);
        float4 x1 = *(const float4*)(x   + sbase + (size_t)STEP_OFS);
        float4 s1 = *(const float4*)(o_s + sbase + (size_t)STEP_OFS);
        uint2 v;
        v.x = cvtpk(x0.x, x0.y); v.y = cvtpk(x0.z, x0.w);
        *(uint2*)((char*)Xh + stofs) = v;
        v.x = cvtpk(s0.x, s0.y); v.y = cvtpk(s0.z, s0.w);
        *(uint2*)((char*)Oh + stofs) = v;
        v.x = cvtpk(x1.x, x1.y); v.y = cvtpk(x1.z, x1.w);
        *(uint2*)((char*)Xh + 2048 + stofs) = v;
        v.x = cvtpk(s1.x, s1.y); v.y = cvtpk(s1.z, s1.w);
        *(uint2*)((char*)Oh + 2048 + stofs) = v;
        uint2 z; z.x = 0u; z.y = 0u;
        *(uint2*)((char*)Hh + t8 * 8) = z;
    }
    float4 xqA = *(const float4*)(x   + sbase + 2 * (size_t)STEP_OFS);
    float4 oqA = *(const float4*)(o_s + sbase + 2 * (size_t)STEP_OFS);
    float4 xqB = *(const float4*)(x   + sbase + 3 * (size_t)STEP_OFS);
    float4 oqB = *(const float4*)(o_s + sbase + 3 * (size_t)STEP_OFS);
    BAR();   // staged t=0/t=1 + zeroed h visible

    // xacc(0): x-part of step 0, from buf0
    f32x4 xF[4], xG[2];
    {
        const char* xb = (const char*)Xh;
        const char* ob = (const char*)Oh;
        const short8 ax0 = *(const short8*)(xb + o0);
        const short8 ax1 = *(const short8*)(xb + o1);
        const short8 ao0 = *(const short8*)(ob + o0);
        const short8 ao1 = *(const short8*)(ob + o1);
        const f32x4 z = {0.f, 0.f, 0.f, 0.f};
        #pragma unroll
        for (int gt = 0; gt < 4; ++gt) {
            f32x4 a = __builtin_amdgcn_mfma_f32_16x16x32_bf16(ax0, fWx[gt][0], z, 0, 0, 0);
            xF[gt]  = __builtin_amdgcn_mfma_f32_16x16x32_bf16(ax1, fWx[gt][1], a, 0, 0, 0);
        }
        #pragma unroll
        for (int gt = 0; gt < 2; ++gt) {
            f32x4 a = __builtin_amdgcn_mfma_f32_16x16x32_bf16(ao0, fGo[gt][0], z, 0, 0, 0);
            xG[gt]  = __builtin_amdgcn_mfma_f32_16x16x32_bf16(ao1, fGo[gt][1], a, 0, 0, 0);
        }
    }
    BAR();   // all waves done reading buf0 before step 0 overwrites it

    auto step = [&](int t, float4& xq, float4& oq) {
        const int p  = t & 1;
        const int pn = p ^ 1;

        // ---- critical path: h(t-1) fragments ------------------------------
        const char* hb = (const char*)Hh + p * 2048;
        const short8 ah0 = *(const short8*)(hb + o0);
        const short8 ah1 = *(const short8*)(hb + o1);
        // ---- filler: x/os(t+1) fragments (independent of h) ---------------
        const char* xbn = (const char*)Xh + pn * 2048;
        const char* obn = (const char*)Oh + pn * 2048;
        const short8 ax0 = *(const short8*)(xbn + o0);
        const short8 ax1 = *(const short8*)(xbn + o1);
        const short8 ao0 = *(const short8*)(obn + o0);
        const short8 ao1 = *(const short8*)(obn + o1);

        // ---- h-MFMAs: finish gates(t) on top of precomputed x-part --------
        f32x4 aF[4], aG[2];
        #pragma unroll
        for (int gt = 0; gt < 4; ++gt) {
            f32x4 a = __builtin_amdgcn_mfma_f32_16x16x32_bf16(ah0, fWh[gt][0], xF[gt], 0, 0, 0);
            aF[gt]  = __builtin_amdgcn_mfma_f32_16x16x32_bf16(ah1, fWh[gt][1], a, 0, 0, 0);
        }
        #pragma unroll
        for (int gt = 0; gt < 2; ++gt) {
            f32x4 a = __builtin_amdgcn_mfma_f32_16x16x32_bf16(ah0, fGh[gt][0], xG[gt], 0, 0, 0);
            aG[gt]  = __builtin_amdgcn_mfma_f32_16x16x32_bf16(ah1, fGh[gt][1], a, 0, 0, 0);
        }

        // ---- x-MFMAs for step t+1 (fills MFMA/EW latency shadow) ----------
        {
            const f32x4 z = {0.f, 0.f, 0.f, 0.f};
            #pragma unroll
            for (int gt = 0; gt < 4; ++gt) {
                f32x4 a = __builtin_amdgcn_mfma_f32_16x16x32_bf16(ax0, fWx[gt][0], z, 0, 0, 0);
                xF[gt]  = __builtin_amdgcn_mfma_f32_16x16x32_bf16(ax1, fWx[gt][1], a, 0, 0, 0);
            }
            #pragma unroll
            for (int gt = 0; gt < 2; ++gt) {
                f32x4 a = __builtin_amdgcn_mfma_f32_16x16x32_bf16(ao0, fGo[gt][0], z, 0, 0, 0);
                xG[gt]  = __builtin_amdgcn_mfma_f32_16x16x32_bf16(ao1, fGo[gt][1], a, 0, 0, 0);
            }
        }

        // ---- stage x/os(t+2) into parity p; reload regs with t+4 ----------
        {
            uint2 sx; sx.x = cvtpk(xq.x, xq.y); sx.y = cvtpk(xq.z, xq.w);
            uint2 so; so.x = cvtpk(oq.x, oq.y); so.y = cvtpk(oq.z, oq.w);
            *(uint2*)((char*)Xh + p * 2048 + stofs) = sx;
            *(uint2*)((char*)Oh + p * 2048 + stofs) = so;
            int tn = t + 4; if (tn > TT - 1) tn = TT - 1;
            xq = *(const float4*)(x   + sbase + (size_t)tn * STEP_OFS);
            oq = *(const float4*)(o_s + sbase + (size_t)tn * STEP_OFS);
        }

        // ---- elementwise: single-rcp cell path, merged tanh*sig(o) --------
        const int tofs = t * STEP_OFS;
        float hv[4];
        #pragma unroll
        for (int e = 0; e < 4; ++e) {
            float ef  = ex2(fmaf(aF[0][e], NL2E, nbf));
            float ei  = ex2(fmaf(aF[1][e], NL2E, nbi));
            float eo  = ex2(fmaf(aF[2][e], NL2E, nbo));
            float eu  = ex2(fmaf(aF[3][e], NL2E, nbu));
            float egf = ex2(fmaf(aG[0][e], NL2E, nbgf));
            float egu = ex2(fmaf(aG[1][e], NL2E, nbgu));
            float P1 = (1.f + ef) * (1.f + egf);
            float P2 = (1.f + ei) * (1.f + eu) * (1.f + egu);
            float c  = fmaf(ct4[e], P2, P1) * frcp(P1 * P2);
            ct4[e] = c;
            float E  = ex2(fminf(c * 2.88539008f, 60.f));   // exact for tanh
            float h  = (E - 1.f) * frcp((E + 1.f) * (1.f + eo));
            hv[e] = h;
            out[obase[e] + tofs] = h;
            if (t == TT - 1) {
                out[HT_OFS + fo[e]] = h;
                out[CT_OFS + fo[e]] = c;
            }
        }

        // ---- h(t) -> LDS parity pn ----------------------------------------
        {
            union { uint32_t u; short s[2]; } h01, h23;
            h01.u = cvtpk(hv[0], hv[1]);
            h23.u = cvtpk(hv[2], hv[3]);
            short* hn = (short*)((char*)Hh + pn * 2048);
            hn[hofs[0]] = h01.s[0];
            hn[hofs[1]] = h01.s[1];
            hn[hofs[2]] = h23.s[0];
            hn[hofs[3]] = h23.s[1];
        }
        BAR();  // h(t) + x/os(t+2) visible
    };

    for (int t = 0; t < TT; t += 2) {
        step(t,     xqA, oqA);
        step(t + 1, xqB, oqB);
    }
}

extern "C" void kernel_launch(void* const* d_in, const int* in_sizes, int n_in,
                              void* d_out, int out_size, void* d_ws, size_t ws_size,
                              hipStream_t stream) {
    const float* x   = (const float*)d_in[0];
    const float* o_s = (const float*)d_in[1];
    const float* U_x = (const float*)d_in[2];
    const float* V_x = (const float*)d_in[3];
    const float* b_x = (const float*)d_in[4];
    const float* U_g = (const float*)d_in[5];
    const float* V_g = (const float*)d_in[6];
    const float* b_g = (const float*)d_in[7];
    float* out = (float*)d_out;

    glstm_kernel<<<dim3(163), dim3(512), 0, stream>>>(x, o_s, U_x, V_x, b_x, U_g, V_g, b_g, out);
}